// Round 1
// baseline (1068.969 us; speedup 1.0000x reference)
//
#include <hip/hip_runtime.h>
#include <stdint.h>

// ============================================================================
// LSTM (B=2048,T=256,D=32,H=256) + FC(256) on gfx950.
// R5: dual batch-tile software pipeline to hide the L3 exchange latency.
// 128 blocks = 64 pairs x 2 col-groups, 512 thr (8 waves). Block owns 32
// batch rows as TWO register-groups (RG0: rows pair*32.., RG1: +16..),
// sharing one 144-VGPR weight set. Per step, phase(RG0) and phase(RG1)
// interleave: RG_i's exchange chain (store slab -> drain -> flag -> sibling
// poll -> load) is in flight while RG_{1-i} computes its GEMM+activations.
// The vmcnt drain before each flag post is deferred into the OTHER phase's
// __syncthreads, so it costs nothing extra. Per-RG A buffers are parity
// double-buffered -> one barrier per phase (2/step vs 2/step before, but
// now the exchange is overlapped instead of serial).
// Pairing (k, k+64): both siblings land on the SAME XCD (k%8==(k+64)%8).
// Flag protocol: flags[pair*4 + R*2 + parity], absolute target
// 2*((t+1)>>1); slab[R][p] holds h_t with p = t&1; h_0 = 0 -> no poll at
// t=0; final exchange after the loop completes h_256 for the FC.
// MFMA layouts (learn_hip verified): A[m=lane&15][k=(lane>>4)*8+j],
// B^T same, C/D: col=lane&15, row=(lane>>4)*4+reg.
// ============================================================================

typedef __attribute__((ext_vector_type(8))) short short8;
typedef __attribute__((ext_vector_type(4))) float f32x4;
typedef unsigned long long ull;

#define LDSTRIDE 296  // 288 K-cols + 8 pad shorts
#define NPAIR 64      // batch pairs (32 rows each)

__device__ __forceinline__ short f2bf(float f) {
  uint32_t u = __builtin_bit_cast(uint32_t, f);
  u = (u + 0x7FFFu + ((u >> 16) & 1u)) >> 16;  // RNE
  return (short)(uint16_t)u;
}

#define LOG2E 1.4426950408889634f
__device__ __forceinline__ float sigmoidf_(float x) {
  return __builtin_amdgcn_rcpf(1.0f + __builtin_amdgcn_exp2f(-LOG2E * x));
}
__device__ __forceinline__ float tanhf_(float x) {
  float t = __builtin_amdgcn_exp2f((2.0f * LOG2E) * x);
  return 1.0f - 2.0f * __builtin_amdgcn_rcpf(t + 1.0f);
}

__global__ void zero_flags(int* flags) { flags[threadIdx.x] = 0; }  // 256 ints

// ---------------------------------------------------------------------------
// Pack W_hh[1024x256] (k 0..255) + W_ih[1024x32] (k 256..287) into bf16 frags.
// frag = ((kt*2 + cg)*8 + hu)*4 + g ; element (lane,j):
//   n = g*256 + cg*128 + hu*16 + (lane&15), k = kt*32 + (lane>>4)*8 + j
// (unchanged from R4 -- weight layout identical)
// ---------------------------------------------------------------------------
__global__ void pack_w(const float* __restrict__ Whh, const float* __restrict__ Wih,
                       short* __restrict__ wpack) {
  int tid = blockIdx.x * 256 + threadIdx.x;  // 576 frags * 64 lanes
  if (tid >= 576 * 64) return;
  int lane = tid & 63;
  int frag = tid >> 6;
  int g = frag & 3, hu = (frag >> 2) & 7, cg = (frag >> 5) & 1, kt = frag >> 6;
  int n = g * 256 + cg * 128 + hu * 16 + (lane & 15);
  int k0 = kt * 32 + (lane >> 4) * 8;
  short8 v;
#pragma unroll
  for (int j = 0; j < 8; ++j) {
    int k = k0 + j;
    float f = (k < 256) ? Whh[n * 256 + k] : Wih[n * 32 + (k - 256)];
    v[j] = f2bf(f);
  }
  *(short8*)(wpack + (size_t)frag * 512 + lane * 8) = v;
}

// W_fc[256x256] -> frags (kt 0..7, ct 0..15): n = ct*16+(lane&15).
__global__ void pack_wfc(const float* __restrict__ Wfc, short* __restrict__ wfc) {
  int tid = blockIdx.x * 256 + threadIdx.x;  // 128 frags * 64 lanes
  if (tid >= 128 * 64) return;
  int lane = tid & 63;
  int frag = tid >> 6;
  int ct = frag & 15, kt = frag >> 4;
  int n = ct * 16 + (lane & 15);
  int k0 = kt * 32 + (lane >> 4) * 8;
  short8 v;
#pragma unroll
  for (int j = 0; j < 8; ++j) v[j] = f2bf(Wfc[n * 256 + k0 + j]);
  *(short8*)(wfc + (size_t)frag * 512 + lane * 8) = v;
}

// slab index (in ull units): [R][parity][pair][cg] x 512 lanes
#define SLAB(R, p, c) ((size_t)((((R)*2 + (p)) * NPAIR + pair) * 2 + (c)) * 512)

// ---------------------------------------------------------------------------
// Main kernel: grid 128; pair = blockIdx&63, cg = blockIdx>>6 (same-XCD pair).
// ---------------------------------------------------------------------------
__global__ __launch_bounds__(512, 2) void lstm_main(
    const float* __restrict__ obs, const short8* __restrict__ wpack,
    const short8* __restrict__ wfc, const float* __restrict__ b_ih,
    const float* __restrict__ b_hh, const float* __restrict__ b_fc,
    ull* __restrict__ xchg, int* __restrict__ flags,
    float* __restrict__ out) {
  // [RG][parity][16 rows x LDSTRIDE]
  __shared__ __align__(16) short A[2][2][16 * LDSTRIDE];
  const int tid = threadIdx.x;
  const int w = tid >> 6, lane = tid & 63;
  const int l15 = lane & 15, quad = lane >> 4;
  const int pair = blockIdx.x & 63, cg = blockIdx.x >> 6;
  const int pairbase = pair * 4;
  const int row0 = pair * 32;              // RG0 rows row0.., RG1 rows row0+16..
  const int xr = tid >> 5, xd = tid & 31;  // x staging: row, d

  // zero all A buffers (h_0 = 0)
  {
    short* Az = &A[0][0][0];
    for (int i = tid; i < 2 * 2 * 16 * LDSTRIDE; i += 512) Az[i] = 0;
  }

  // persistent weight registers: 36 frags = 144 VGPR, shared by both RGs
  short8 wfr[9][4];
#pragma unroll
  for (int kt = 0; kt < 9; ++kt)
#pragma unroll
    for (int g = 0; g < 4; ++g)
      wfr[kt][g] = wpack[(size_t)(((kt * 2 + cg) * 8 + w) * 4 + g) * 64 + lane];

  // fused bias per gate for this lane's hidden unit (col = cg*128+w*16+l15)
  float bias[4];
#pragma unroll
  for (int g = 0; g < 4; ++g) {
    int idx = g * 256 + cg * 128 + w * 16 + l15;
    bias[g] = b_ih[idx] + b_hh[idx];
  }

  float c0[4], c1[4];
#pragma unroll
  for (int i = 0; i < 4; ++i) { c0[i] = 0.f; c1[i] = 0.f; }

  __syncthreads();  // zeroing done before x_0 staging overwrites x-cols
  A[0][0][xr * LDSTRIDE + 256 + xd] =
      f2bf(obs[((size_t)(row0 + xr) * 256 + 0) * 32 + xd]);
  A[1][0][xr * LDSTRIDE + 256 + xd] =
      f2bf(obs[((size_t)(row0 + 16 + xr) * 256 + 0) * 32 + xd]);
  // (phase-0 t=0 __syncthreads makes staging visible before first GEMM)

  // One phase of the 2-stage pipeline. Order within a phase:
  //  1. issue obs prefetch (consumed at phase end)
  //  2. poll sibling flag for h_t, load sibling slab, write into Acur
  //  3. __syncthreads  -- makes (2) visible AND drains the PREVIOUS phase's
  //     slab stores in every wave -> safe to post the previous phase's flag
  //  4. tid0 posts flag for the slab stored by the previous phase
  //  5. GEMM over Acur -> gates -> own h_{t+1}; store own slab (async)
  //  6. write own h_{t+1} + x_{t+1} into Anx (other parity; no barrier needed,
  //     next phase's __syncthreads covers visibility before its next read)
#define PHASE(R, ROWBASE, CST)                                                   \
  do {                                                                           \
    short* __restrict__ Acur = &A[R][t & 1][0];                                  \
    short* __restrict__ Anx = &A[R][(t + 1) & 1][0];                             \
    const float xv = obs[((size_t)((ROWBASE) + xr) * 256 + tn) * 32 + xd];       \
    if (t > 0) {                                                                 \
      const int fi = pairbase + (R)*2 + (t & 1);                                 \
      const int tgt = 2 * ((t + 1) >> 1);                                        \
      while (__hip_atomic_load(&flags[fi], __ATOMIC_RELAXED,                     \
                               __HIP_MEMORY_SCOPE_AGENT) < tgt) {                \
      }                                                                          \
      ull* sslab = xchg + SLAB(R, t & 1, cg ^ 1) + w * 64 + lane;                \
      const ull sv = __hip_atomic_load(sslab, __ATOMIC_RELAXED,                  \
                                       __HIP_MEMORY_SCOPE_AGENT);               \
      _Pragma("unroll") for (int reg = 0; reg < 4; ++reg)                        \
          Acur[(quad * 4 + reg) * LDSTRIDE + (cg ^ 1) * 128 + w * 16 + l15] =    \
          (short)(uint16_t)(sv >> (16 * reg));                                   \
    }                                                                            \
    __syncthreads();                                                             \
    if (tid == 0) {                                                              \
      if ((R) == 1)                                                              \
        __hip_atomic_fetch_add(&flags[pairbase + 0 + ((t + 1) & 1)], 1,          \
                               __ATOMIC_RELAXED, __HIP_MEMORY_SCOPE_AGENT);      \
      else if (t > 0)                                                            \
        __hip_atomic_fetch_add(&flags[pairbase + 2 + (t & 1)], 1,                \
                               __ATOMIC_RELAXED, __HIP_MEMORY_SCOPE_AGENT);      \
    }                                                                            \
    f32x4 acc[4];                                                                \
    _Pragma("unroll") for (int g = 0; g < 4; ++g) acc[g] =                       \
        (f32x4){bias[g], bias[g], bias[g], bias[g]};                             \
    short8 acur = *(const short8*)&Acur[l15 * LDSTRIDE + quad * 8];              \
    _Pragma("unroll") for (int kt = 0; kt < 9; ++kt) {                           \
      short8 anext;                                                              \
      if (kt < 8)                                                                \
        anext = *(const short8*)&Acur[l15 * LDSTRIDE + (kt + 1) * 32 + quad * 8];\
      _Pragma("unroll") for (int g = 0; g < 4; ++g) acc[g] =                     \
          __builtin_amdgcn_mfma_f32_16x16x32_bf16(acur, wfr[kt][g], acc[g], 0,   \
                                                  0, 0);                         \
      if (kt < 8) acur = anext;                                                  \
    }                                                                            \
    short hb[4];                                                                 \
    _Pragma("unroll") for (int reg = 0; reg < 4; ++reg) {                        \
      float iv = sigmoidf_(acc[0][reg]);                                         \
      float fv = sigmoidf_(acc[1][reg]);                                         \
      float gv = tanhf_(acc[2][reg]);                                            \
      float ov = sigmoidf_(acc[3][reg]);                                         \
      float cc = fv * (CST)[reg] + iv * gv;                                      \
      (CST)[reg] = cc;                                                           \
      hb[reg] = f2bf(ov * tanhf_(cc));                                           \
    }                                                                            \
    const ull hv = (ull)(uint16_t)hb[0] | ((ull)(uint16_t)hb[1] << 16) |         \
                   ((ull)(uint16_t)hb[2] << 32) | ((ull)(uint16_t)hb[3] << 48);  \
    __hip_atomic_store(xchg + SLAB(R, (t + 1) & 1, cg) + w * 64 + lane, hv,      \
                       __ATOMIC_RELAXED, __HIP_MEMORY_SCOPE_AGENT);              \
    _Pragma("unroll") for (int reg = 0; reg < 4; ++reg)                          \
        Anx[(quad * 4 + reg) * LDSTRIDE + cg * 128 + w * 16 + l15] = hb[reg];    \
    Anx[xr * LDSTRIDE + 256 + xd] = f2bf(xv);                                    \
  } while (0)

  for (int t = 0; t < 256; ++t) {
    const int tn = (t < 255) ? (t + 1) : 255;
    PHASE(0, row0, c0);
    PHASE(1, row0 + 16, c1);
  }
#undef PHASE

  // ---- final exchange: complete h_256 (parity 0) in A[R][0] for the FC ----
  __syncthreads();  // drains phase(1,255) slab1 stores in all waves
  if (tid == 0)
    __hip_atomic_fetch_add(&flags[pairbase + 2 + 0], 1, __ATOMIC_RELAXED,
                           __HIP_MEMORY_SCOPE_AGENT);
  {
    const int tgt = 256;  // 2 * ((256+1)>>1)
    while (__hip_atomic_load(&flags[pairbase + 0 + 0], __ATOMIC_RELAXED,
                             __HIP_MEMORY_SCOPE_AGENT) < tgt) {
    }
    ull sv = __hip_atomic_load(xchg + SLAB(0, 0, cg ^ 1) + w * 64 + lane,
                               __ATOMIC_RELAXED, __HIP_MEMORY_SCOPE_AGENT);
#pragma unroll
    for (int reg = 0; reg < 4; ++reg)
      A[0][0][(quad * 4 + reg) * LDSTRIDE + (cg ^ 1) * 128 + w * 16 + l15] =
          (short)(uint16_t)(sv >> (16 * reg));
    while (__hip_atomic_load(&flags[pairbase + 2 + 0], __ATOMIC_RELAXED,
                             __HIP_MEMORY_SCOPE_AGENT) < tgt) {
    }
    ull sv1 = __hip_atomic_load(xchg + SLAB(1, 0, cg ^ 1) + w * 64 + lane,
                                __ATOMIC_RELAXED, __HIP_MEMORY_SCOPE_AGENT);
#pragma unroll
    for (int reg = 0; reg < 4; ++reg)
      A[1][0][(quad * 4 + reg) * LDSTRIDE + (cg ^ 1) * 128 + w * 16 + l15] =
          (short)(uint16_t)(sv1 >> (16 * reg));
  }
  __syncthreads();

  // FC epilogue: wave w -> cols (cg*8+w)*16..+16, rows pair*32..+32 (both RGs)
  const int ct = cg * 8 + w;
  const int col = ct * 16 + l15;
  const float bv = b_fc[col];
#pragma unroll
  for (int R2 = 0; R2 < 2; ++R2) {
    const short* Af = &A[R2][0][0];
    f32x4 ao = (f32x4){0.f, 0.f, 0.f, 0.f};
#pragma unroll
    for (int kt = 0; kt < 8; ++kt) {
      const short8 a = *(const short8*)&Af[l15 * LDSTRIDE + kt * 32 + quad * 8];
      const short8 b = wfc[(size_t)(kt * 16 + ct) * 64 + lane];
      ao = __builtin_amdgcn_mfma_f32_16x16x32_bf16(a, b, ao, 0, 0, 0);
    }
#pragma unroll
    for (int reg = 0; reg < 4; ++reg) {
      const int row = row0 + R2 * 16 + quad * 4 + reg;
      out[(size_t)row * 256 + col] = ao[reg] + bv;
    }
  }
}

extern "C" void kernel_launch(void* const* d_in, const int* in_sizes, int n_in,
                              void* d_out, int out_size, void* d_ws, size_t ws_size,
                              hipStream_t stream) {
  const float* obs  = (const float*)d_in[0];   // [2048,256,32]
  const float* W_ih = (const float*)d_in[1];   // [1024,32]
  const float* W_hh = (const float*)d_in[2];   // [1024,256]
  const float* b_ih = (const float*)d_in[3];   // [1024]
  const float* b_hh = (const float*)d_in[4];   // [1024]
  const float* W_fc = (const float*)d_in[5];   // [256,256]
  const float* b_fc = (const float*)d_in[6];   // [256]
  float* out = (float*)d_out;                  // [2048,256]

  // ws layout
  int*   flags = (int*)d_ws;                       // 256 ints (1 KB)
  short* wpack = (short*)((char*)d_ws + 1024);     // 576*512 shorts = 576 KB
  short* wfcp  = wpack + 576 * 512;                // 128*512 shorts = 128 KB
  ull*   xchg  = (ull*)(wfcp + 128 * 512);         // 2RG*2par*64pair*2cg*512*8B = 2 MB

  hipLaunchKernelGGL(zero_flags, dim3(1), dim3(256), 0, stream, flags);
  hipLaunchKernelGGL(pack_w, dim3(144), dim3(256), 0, stream, W_hh, W_ih, wpack);
  hipLaunchKernelGGL(pack_wfc, dim3(32), dim3(256), 0, stream, W_fc, wfcp);
  hipLaunchKernelGGL(lstm_main, dim3(128), dim3(512), 0, stream, obs,
                     (const short8*)wpack, (const short8*)wfcp,
                     b_ih, b_hh, b_fc, xchg, flags, out);
}

// Round 2
// 745.958 us; speedup vs baseline: 1.4330x; 1.4330x over previous
//
#include <hip/hip_runtime.h>
#include <stdint.h>

// ============================================================================
// LSTM (B=2048,T=256,D=32,H=256) + FC(256) on gfx950.
// R6: flag-free tagged exchange + local/remote K-split to hide it.
// 256 blocks = 128 batch-tiles x 2 col-groups (pairing b <-> b+128, same XCD),
// 512 thr (8 waves), 1 block/CU. Wave w owns hidden units cg*128+w*16..+16,
// all 4 gates; 36 weight frags (9 ktiles x 4 gates) persistent in regs.
// Per step, GEMM splits: LOCAL ktiles (own h-half kt=cg*4..+3, x kt=8) need
// no sibling data; REMOTE ktiles ((cg^1)*4..+3) need sibling h_t. Exchange is
// two 8B relaxed agent atomics per lane, each tagged with the step number in
// bits 63:48 (|h|<1 -> payload never aliases tag; parity double-buffer +
// the h_{t+1}-needs-h_t dependence makes WAR safe; zero-init => tag0 != 1).
// Schedule: issue sibling loads -> local GEMM (cover) -> tag-check/poll ->
// LDS-write sib half -> barrier -> remote GEMM -> gates -> store tagged slab.
// No flags, no tid0 serialization, no vmcnt-drain-before-post requirement.
// MFMA layouts (learn_hip verified): A[m=lane&15][k=(lane>>4)*8+j],
// B^T same, C/D: col=lane&15, row=(lane>>4)*4+reg.
// ============================================================================

typedef __attribute__((ext_vector_type(8))) short short8;
typedef __attribute__((ext_vector_type(4))) float f32x4;
typedef unsigned long long ull;

#define LDSTRIDE 296  // 288 K-cols + 8 pad shorts
#define NBT 128       // batch tiles

__device__ __forceinline__ short f2bf(float f) {
  uint32_t u = __builtin_bit_cast(uint32_t, f);
  u = (u + 0x7FFFu + ((u >> 16) & 1u)) >> 16;  // RNE
  return (short)(uint16_t)u;
}

#define LOG2E 1.4426950408889634f
__device__ __forceinline__ float sigmoidf_(float x) {
  return __builtin_amdgcn_rcpf(1.0f + __builtin_amdgcn_exp2f(-LOG2E * x));
}
__device__ __forceinline__ float tanhf_(float x) {
  float t = __builtin_amdgcn_exp2f((2.0f * LOG2E) * x);
  return 1.0f - 2.0f * __builtin_amdgcn_rcpf(t + 1.0f);
}

// zero the 4MB xchg buffer (tags must start != 1..256)
__global__ void zero_xchg(ull* __restrict__ x) {
  size_t i = ((size_t)blockIdx.x * 256 + threadIdx.x) * 4;
  x[i] = 0; x[i + 1] = 0; x[i + 2] = 0; x[i + 3] = 0;
}

// ---------------------------------------------------------------------------
// Pack W_hh[1024x256] (k 0..255) + W_ih[1024x32] (k 256..287) into bf16 frags.
// frag = ((kt*2 + cg)*8 + hu)*4 + g ; element (lane,j):
//   n = g*256 + cg*128 + hu*16 + (lane&15), k = kt*32 + (lane>>4)*8 + j
// ---------------------------------------------------------------------------
__global__ void pack_w(const float* __restrict__ Whh, const float* __restrict__ Wih,
                       short* __restrict__ wpack) {
  int tid = blockIdx.x * 256 + threadIdx.x;  // 576 frags * 64 lanes
  if (tid >= 576 * 64) return;
  int lane = tid & 63;
  int frag = tid >> 6;
  int g = frag & 3, hu = (frag >> 2) & 7, cg = (frag >> 5) & 1, kt = frag >> 6;
  int n = g * 256 + cg * 128 + hu * 16 + (lane & 15);
  int k0 = kt * 32 + (lane >> 4) * 8;
  short8 v;
#pragma unroll
  for (int j = 0; j < 8; ++j) {
    int k = k0 + j;
    float f = (k < 256) ? Whh[n * 256 + k] : Wih[n * 32 + (k - 256)];
    v[j] = f2bf(f);
  }
  *(short8*)(wpack + (size_t)frag * 512 + lane * 8) = v;
}

// W_fc[256x256] -> frags (kt 0..7, ct 0..15): n = ct*16+(lane&15).
__global__ void pack_wfc(const float* __restrict__ Wfc, short* __restrict__ wfc) {
  int tid = blockIdx.x * 256 + threadIdx.x;  // 128 frags * 64 lanes
  if (tid >= 128 * 64) return;
  int lane = tid & 63;
  int frag = tid >> 6;
  int ct = frag & 15, kt = frag >> 4;
  int n = ct * 16 + (lane & 15);
  int k0 = kt * 32 + (lane >> 4) * 8;
  short8 v;
#pragma unroll
  for (int j = 0; j < 8; ++j) v[j] = f2bf(Wfc[n * 256 + k0 + j]);
  *(short8*)(wfc + (size_t)frag * 512 + lane * 8) = v;
}

// slab word index (ull units): [parity][bt][cg][tid][word0/1]
#define SLAB(p, c) ((size_t)((((p)*NBT + bt) * 2 + (c)) * 512 + tid) * 2)

// ---------------------------------------------------------------------------
// Main kernel: grid 256; bt = blockIdx&127, cg = blockIdx>>7 (same-XCD pair).
// ---------------------------------------------------------------------------
__global__ __launch_bounds__(512, 2) void lstm_main(
    const float* __restrict__ obs, const short8* __restrict__ wpack,
    const short8* __restrict__ wfc, const float* __restrict__ b_ih,
    const float* __restrict__ b_hh, const float* __restrict__ b_fc,
    ull* __restrict__ xchg, float* __restrict__ out) {
  __shared__ __align__(16) short A[2][16 * LDSTRIDE];  // parity double-buffer
  const int tid = threadIdx.x;
  const int w = tid >> 6, lane = tid & 63;
  const int l15 = lane & 15, quad = lane >> 4;
  const int bt = blockIdx.x & 127, cg = blockIdx.x >> 7;
  const int row0 = bt * 16;
  const int xr = tid >> 5, xd = tid & 31;  // x staging: row, d
  const int kro = (cg ^ 1) * 4;            // remote ktile base
  const int klo = cg * 4;                  // local ktile base

  // zero both A buffers (h_0 = 0)
  {
    short* Az = &A[0][0];
    for (int i = tid; i < 2 * 16 * LDSTRIDE; i += 512) Az[i] = 0;
  }

  // persistent weight registers: 36 frags = 144 regs (constant indices only)
  short8 wfr[9][4];
#pragma unroll
  for (int kt = 0; kt < 9; ++kt)
#pragma unroll
    for (int g = 0; g < 4; ++g)
      wfr[kt][g] = wpack[(size_t)(((kt * 2 + cg) * 8 + w) * 4 + g) * 64 + lane];

  // fused bias per gate for this lane's hidden unit (col = cg*128+w*16+l15)
  float bias[4];
#pragma unroll
  for (int g = 0; g < 4; ++g) {
    int idx = g * 256 + cg * 128 + w * 16 + l15;
    bias[g] = b_ih[idx] + b_hh[idx];
  }

  float c4[4];
#pragma unroll
  for (int i = 0; i < 4; ++i) c4[i] = 0.f;

  __syncthreads();  // zeroing done
  A[0][xr * LDSTRIDE + 256 + xd] =
      f2bf(obs[((size_t)(row0 + xr) * 256 + 0) * 32 + xd]);
  __syncthreads();  // x_0 staged

// 4 MFMAs (all gates) for one compile-time ktile (wfr index must be constant)
#define MFK(KT)                                                                \
  {                                                                            \
    const short8 a_ =                                                          \
        *(const short8*)&Acur[l15 * LDSTRIDE + (KT)*32 + quad * 8];            \
    acc[0] = __builtin_amdgcn_mfma_f32_16x16x32_bf16(a_, wfr[KT][0], acc[0],   \
                                                     0, 0, 0);                 \
    acc[1] = __builtin_amdgcn_mfma_f32_16x16x32_bf16(a_, wfr[KT][1], acc[1],   \
                                                     0, 0, 0);                 \
    acc[2] = __builtin_amdgcn_mfma_f32_16x16x32_bf16(a_, wfr[KT][2], acc[2],   \
                                                     0, 0, 0);                 \
    acc[3] = __builtin_amdgcn_mfma_f32_16x16x32_bf16(a_, wfr[KT][3], acc[3],   \
                                                     0, 0, 0);                 \
  }

  for (int t = 0; t < 256; ++t) {
    const int p = t & 1;
    short* __restrict__ Acur = &A[p][0];
    short* __restrict__ Anx = &A[p ^ 1][0];
    const int tn = (t < 255) ? (t + 1) : 255;
    // prefetch x_{t+1} (consumed at phase 6)
    const float xv = obs[((size_t)(row0 + xr) * 256 + tn) * 32 + xd];

    // early-issue sibling slab loads (latency overlaps local GEMM)
    const ull* __restrict__ ss = xchg + SLAB(p, cg ^ 1);
    ull s0 = 0, s1 = 0;
    if (t > 0) {
      s0 = __hip_atomic_load(&ss[0], __ATOMIC_RELAXED, __HIP_MEMORY_SCOPE_AGENT);
      s1 = __hip_atomic_load(&ss[1], __ATOMIC_RELAXED, __HIP_MEMORY_SCOPE_AGENT);
    }

    // phase 1: LOCAL GEMM (own h-half + x) -- needs nothing from sibling
    f32x4 acc[4];
#pragma unroll
    for (int g = 0; g < 4; ++g)
      acc[g] = (f32x4){bias[g], bias[g], bias[g], bias[g]};
    if (cg == 0) { MFK(0) MFK(1) MFK(2) MFK(3) }
    else         { MFK(4) MFK(5) MFK(6) MFK(7) }
    MFK(8)  // x ktile

    // phase 2: tag-check / poll sibling h_t, scatter into Acur sib-half
    if (t > 0) {
      const ull tg = (ull)t;
      while ((s0 >> 48) != tg || (s1 >> 48) != tg) {
        s0 = __hip_atomic_load(&ss[0], __ATOMIC_RELAXED, __HIP_MEMORY_SCOPE_AGENT);
        s1 = __hip_atomic_load(&ss[1], __ATOMIC_RELAXED, __HIP_MEMORY_SCOPE_AGENT);
      }
      const int scol = kro * 32 + w * 16 + l15;
      Acur[(quad * 4 + 0) * LDSTRIDE + scol] = (short)(uint16_t)s0;
      Acur[(quad * 4 + 1) * LDSTRIDE + scol] = (short)(uint16_t)(s0 >> 16);
      Acur[(quad * 4 + 2) * LDSTRIDE + scol] = (short)(uint16_t)s1;
      Acur[(quad * 4 + 3) * LDSTRIDE + scol] = (short)(uint16_t)(s1 >> 16);
    }
    __syncthreads();  // phase 3: sib-half visible to all waves

    // phase 4: REMOTE GEMM (sibling h-half)
    if (cg == 0) { MFK(4) MFK(5) MFK(6) MFK(7) }
    else         { MFK(0) MFK(1) MFK(2) MFK(3) }

    // phase 5: gates
    short hb[4];
#pragma unroll
    for (int reg = 0; reg < 4; ++reg) {
      float iv = sigmoidf_(acc[0][reg]);
      float fv = sigmoidf_(acc[1][reg]);
      float gv = tanhf_(acc[2][reg]);
      float ov = sigmoidf_(acc[3][reg]);
      float cc = fv * c4[reg] + iv * gv;
      c4[reg] = cc;
      hb[reg] = f2bf(ov * tanhf_(cc));
    }

    // phase 6: tagged slab store (tag t+1) FIRST, then LDS writes
    {
      const ull tg1 = (ull)(t + 1) << 48;
      ull* __restrict__ ds = xchg + SLAB((t + 1) & 1, cg);
      __hip_atomic_store(&ds[0],
                         tg1 | ((ull)(uint16_t)hb[1] << 16) | (ull)(uint16_t)hb[0],
                         __ATOMIC_RELAXED, __HIP_MEMORY_SCOPE_AGENT);
      __hip_atomic_store(&ds[1],
                         tg1 | ((ull)(uint16_t)hb[3] << 16) | (ull)(uint16_t)hb[2],
                         __ATOMIC_RELAXED, __HIP_MEMORY_SCOPE_AGENT);
    }
    {
      const int ocol = klo * 32 + w * 16 + l15;
#pragma unroll
      for (int reg = 0; reg < 4; ++reg)
        Anx[(quad * 4 + reg) * LDSTRIDE + ocol] = hb[reg];
      Anx[xr * LDSTRIDE + 256 + xd] = f2bf(xv);
    }
    __syncthreads();  // phase 7: own-half h_{t+1} + x_{t+1} visible
  }
#undef MFK

  // ---- final exchange: complete h_256 (parity 0, tag 256) for the FC ----
  {
    const ull* __restrict__ ss = xchg + SLAB(0, cg ^ 1);
    ull s0 = __hip_atomic_load(&ss[0], __ATOMIC_RELAXED, __HIP_MEMORY_SCOPE_AGENT);
    ull s1 = __hip_atomic_load(&ss[1], __ATOMIC_RELAXED, __HIP_MEMORY_SCOPE_AGENT);
    while ((s0 >> 48) != 256ull || (s1 >> 48) != 256ull) {
      s0 = __hip_atomic_load(&ss[0], __ATOMIC_RELAXED, __HIP_MEMORY_SCOPE_AGENT);
      s1 = __hip_atomic_load(&ss[1], __ATOMIC_RELAXED, __HIP_MEMORY_SCOPE_AGENT);
    }
    const int scol = kro * 32 + w * 16 + l15;
    A[0][(quad * 4 + 0) * LDSTRIDE + scol] = (short)(uint16_t)s0;
    A[0][(quad * 4 + 1) * LDSTRIDE + scol] = (short)(uint16_t)(s0 >> 16);
    A[0][(quad * 4 + 2) * LDSTRIDE + scol] = (short)(uint16_t)s1;
    A[0][(quad * 4 + 3) * LDSTRIDE + scol] = (short)(uint16_t)(s1 >> 16);
  }
  __syncthreads();

  // FC epilogue: wave w -> out rows bt*16..+16, cols (cg*8+w)*16..+16
  {
    const int ct = cg * 8 + w;
    const int col = ct * 16 + l15;
    const float bv = b_fc[col];
    f32x4 ao = (f32x4){0.f, 0.f, 0.f, 0.f};
#pragma unroll
    for (int kt = 0; kt < 8; ++kt) {
      const short8 a = *(const short8*)&A[0][l15 * LDSTRIDE + kt * 32 + quad * 8];
      const short8 b = wfc[(size_t)(kt * 16 + ct) * 64 + lane];
      ao = __builtin_amdgcn_mfma_f32_16x16x32_bf16(a, b, ao, 0, 0, 0);
    }
#pragma unroll
    for (int reg = 0; reg < 4; ++reg) {
      const int row = row0 + quad * 4 + reg;
      out[(size_t)row * 256 + col] = ao[reg] + bv;
    }
  }
}

extern "C" void kernel_launch(void* const* d_in, const int* in_sizes, int n_in,
                              void* d_out, int out_size, void* d_ws, size_t ws_size,
                              hipStream_t stream) {
  const float* obs  = (const float*)d_in[0];   // [2048,256,32]
  const float* W_ih = (const float*)d_in[1];   // [1024,32]
  const float* W_hh = (const float*)d_in[2];   // [1024,256]
  const float* b_ih = (const float*)d_in[3];   // [1024]
  const float* b_hh = (const float*)d_in[4];   // [1024]
  const float* W_fc = (const float*)d_in[5];   // [256,256]
  const float* b_fc = (const float*)d_in[6];   // [256]
  float* out = (float*)d_out;                  // [2048,256]

  // ws layout
  short* wpack = (short*)d_ws;                       // 576*512 shorts = 576 KB
  short* wfcp  = wpack + 576 * 512;                  // 128*512 shorts = 128 KB
  ull*   xchg  = (ull*)((char*)d_ws + (576 + 128) * 1024);  // 4 MB tagged slabs

  hipLaunchKernelGGL(zero_xchg, dim3(512), dim3(256), 0, stream, xchg);
  hipLaunchKernelGGL(pack_w, dim3(144), dim3(256), 0, stream, W_hh, W_ih, wpack);
  hipLaunchKernelGGL(pack_wfc, dim3(32), dim3(256), 0, stream, W_fc, wfcp);
  hipLaunchKernelGGL(lstm_main, dim3(256), dim3(512), 0, stream, obs,
                     (const short8*)wpack, (const short8*)wfcp,
                     b_ih, b_hh, b_fc, xchg, out);
}